// Round 11
// baseline (212.240 us; speedup 1.0000x reference)
//
#include <hip/hip_runtime.h>

// LoRA: out = x @ (A@B) * 1.0, computed as (x@A)@B, FUSED, occupancy-first.
// x: [M=16384, K=4096] f32, A: [K, 16] f32, B: [16, N=4096] f32.
//
// Phase 1: 512-thread blocks, 16 rows. Wave w = (row-group rg=w&3, j-half
// jg=w>>2): 4 rows x 8 j per wave -> vals[32] (halves register pressure vs
// r9's vals[64] while keeping 4-row amortization of LDS A-reads: 2 b128 per
// 64-FMA k-block). Target <=64 actual VGPR -> 8 waves/SIMD (vs r9's ~4) to
// hide x-load latency, the diagnosed limiter. x loads stay scalar dword
// (r2-proven); j-halves duplicate them (L1 hits).
// Phase 2: out = Ts @ B with float2 B-fragments (32 regs, so phase 2 doesn't
// inflate the kernel's VGPR peak); still write-roofline-bound.

constexpr int RANK = 16;
constexpr int K = 4096;
constexpr int N = 4096;
constexpr int M = 4 * 4096;
constexpr int KC = 512;        // K-chunk staged in LDS (512 rows x 64B = 32KB)
constexpr int NCHUNK = K / KC; // 8

__global__ __launch_bounds__(512, 6) void lora_fused(const float* __restrict__ x,
                                                     const float* __restrict__ A,
                                                     const float* __restrict__ B,
                                                     float* __restrict__ out) {
  const int tid = threadIdx.x;
  const int lane = tid & 63;
  const int w = tid >> 6;
  const int rg = w & 3;        // row group (4 rows)
  const int jg = w >> 2;       // j half (8 of 16 outputs)
  const int rbase = blockIdx.x * 16;
  const int r0 = rbase + rg * 4;
  const int m = (lane >> 2) & 3;

  __shared__ float4 As[KC * 4];  // 32 KB, swizzled A chunk (r2 layout)
  __shared__ float Ts[16][RANK]; // 1 KB, block's T-tile

  const float4* __restrict__ A4 = reinterpret_cast<const float4*>(A);

  // ================= Phase 1: T-tile = x @ A =============
  float vals[32];
#pragma unroll
  for (int i = 0; i < 32; ++i) vals[i] = 0.0f;

  for (int c = 0; c < NCHUNK; ++c) {
    __syncthreads();  // previous chunk's readers done
    // ---- stage chunk c: 2048 float4 slots, 4 per thread (512 thr) ----
    // slot s of row k stored at p = s ^ ((k>>2)&3)  (r2 swizzle, proven)
#pragma unroll
    for (int q = 0; q < 4; ++q) {
      const int n = q * 512 + tid;              // slot index 0..2047
      const int k = n >> 2;                     // local row
      const int s = n & 3;                      // true slot
      const int p = s ^ ((k >> 2) & 3);         // swizzled position
      As[k * 4 + p] = A4[(size_t)c * 2048 + n];
    }
    __syncthreads();

    // ---- compute: 8 k-blocks of 64 (one k per lane) ----
#pragma unroll
    for (int kbi = 0; kbi < 8; ++kbi) {
      const int kl = kbi * 64 + lane;           // local k in chunk
      const size_t kg = (size_t)c * KC + kl;    // global k

      float xv[4];
#pragma unroll
      for (int r = 0; r < 4; ++r) xv[r] = x[(size_t)(r0 + r) * K + kg];

      // this wave's 2 j-slots (j = jg*8 .. jg*8+7), swizzle-inverted read:
      // bank pattern: 4 distinct 16B slots x 2 lanes per 128B period = free.
      float4 a[2];
#pragma unroll
      for (int ss = 0; ss < 2; ++ss)
        a[ss] = As[kl * 4 + ((2 * jg + ss) ^ m)];

#pragma unroll
      for (int r = 0; r < 4; ++r) {
#pragma unroll
        for (int ss = 0; ss < 2; ++ss) {
          vals[r * 8 + ss * 4 + 0] = fmaf(xv[r], a[ss].x, vals[r * 8 + ss * 4 + 0]);
          vals[r * 8 + ss * 4 + 1] = fmaf(xv[r], a[ss].y, vals[r * 8 + ss * 4 + 1]);
          vals[r * 8 + ss * 4 + 2] = fmaf(xv[r], a[ss].z, vals[r * 8 + ss * 4 + 2]);
          vals[r * 8 + ss * 4 + 3] = fmaf(xv[r], a[ss].w, vals[r * 8 + ss * 4 + 3]);
        }
      }
    }
  }

  // 5-fold reduce-scatter over lane bits {32,16,8,4,2} (r7-proven mechanics,
  // 32-element array), then butterfly over bit 1 completes the sum.
  // Even lane 2e holds element e = r*8 + jj  (r = e>>3, jj = e&7).
#define FOLD(AH, LB)                                           \
  {                                                            \
    const bool hi = (lane & (LB)) != 0;                        \
    _Pragma("unroll")                                          \
    for (int i = 0; i < (AH); ++i) {                           \
      const float send = hi ? vals[i] : vals[i + (AH)];        \
      const float keep = hi ? vals[i + (AH)] : vals[i];        \
      vals[i] = keep + __shfl_xor(send, (LB), 64);             \
    }                                                          \
  }
  FOLD(16, 32)
  FOLD(8, 16)
  FOLD(4, 8)
  FOLD(2, 4)
  FOLD(1, 2)
#undef FOLD
  vals[0] += __shfl_xor(vals[0], 1, 64);

  if (!(lane & 1)) {
    const int e = lane >> 1;  // 0..31
    Ts[rg * 4 + (e >> 3)][jg * 8 + (e & 7)] = vals[0];
  }
  __syncthreads();

  // ================= Phase 2: out-tile = T-tile @ B ==================
  // Wave w owns cols [w*512, w*512+512), 4 passes of 128 cols (float2/lane).
  const float2* __restrict__ B2 = reinterpret_cast<const float2*>(B);
  float2* __restrict__ out2 = reinterpret_cast<float2*>(out);

#pragma unroll 1
  for (int cc = 0; cc < 4; ++cc) {
    const int col = w * 512 + cc * 128 + lane * 2;

    float2 b[16];  // 32 VGPRs (keeps phase-2 peak under phase-1's)
#pragma unroll
    for (int j = 0; j < RANK; ++j) b[j] = B2[((size_t)j * N + col) >> 1];

#pragma unroll 1
    for (int r = 0; r < 16; ++r) {
      // Broadcast T row r (same addr all lanes -> free LDS broadcast).
      const float4* __restrict__ tr4 =
          reinterpret_cast<const float4*>(&Ts[r][0]);
      const float4 t0 = tr4[0];
      const float4 t1 = tr4[1];
      const float4 t2 = tr4[2];
      const float4 t3 = tr4[3];
      const float tsv[16] = {t0.x, t0.y, t0.z, t0.w, t1.x, t1.y, t1.z, t1.w,
                             t2.x, t2.y, t2.z, t2.w, t3.x, t3.y, t3.z, t3.w};

      float2 acc;
      acc.x = acc.y = 0.0f;
#pragma unroll
      for (int j = 0; j < RANK; ++j) {
        acc.x = fmaf(tsv[j], b[j].x, acc.x);
        acc.y = fmaf(tsv[j], b[j].y, acc.y);
      }
      out2[((size_t)(rbase + r) * N + col) >> 1] = acc;
    }
  }
}

extern "C" void kernel_launch(void* const* d_in, const int* in_sizes, int n_in,
                              void* d_out, int out_size, void* d_ws, size_t ws_size,
                              hipStream_t stream) {
  const float* x = (const float*)d_in[0];   // [M, K]
  const float* A = (const float*)d_in[1];   // [K, RANK]
  const float* B = (const float*)d_in[2];   // [RANK, N]
  float* out = (float*)d_out;               // [M, N]
  (void)d_ws; (void)ws_size;

  // One fused kernel: 16 rows per block -> 1024 blocks of 512 threads
  // (exactly one full residency round at 4 blocks/CU).
  lora_fused<<<M / 16, 512, 0, stream>>>(x, A, B, out);
}

// Round 12
// 143.709 us; speedup vs baseline: 1.4769x; 1.4769x over previous
//
#include <hip/hip_runtime.h>

// LoRA: out = x @ (A@B) * 1.0, computed as (x@A)@B, FUSED.
// x: [M=16384, K=4096] f32, A: [K, 16] f32, B: [16, N=4096] f32.
//
// Phase 1 (deep-MLP design): block = 256 thr (4 waves), 8 rows. Wave w owns
// j-quad w for ALL 8 rows -> vals[32]. Per k-block each lane owns k-quad
// q = kb*64+lane and issues EIGHT independent float4 x-loads (8 rows,
// 128 B/lane in flight -- 8x r2's depth; the diagnosed limiter is
// outstanding read bytes). A-chunk in LDS with r2's proven store swizzle
// (slot s of row k at p = s^((k>>2)&3)); read a[i] = As[(4q+i)*4+(jq^(lane&3))]
// (worst-case 4-way on a small LDS share). NO launch_bounds minimum --
// r11 showed strangling regalloc (VGPR 40) serializes loads.
// Phase 2: r9's write-roofline T@B adapted to the 8-row tile.

constexpr int RANK = 16;
constexpr int K = 4096;
constexpr int N = 4096;
constexpr int M = 4 * 4096;
constexpr int KC = 512;        // K-chunk staged in LDS (512 rows x 64B = 32KB)
constexpr int NCHUNK = K / KC; // 8
constexpr int ROWSB = 8;       // rows per block

__global__ __launch_bounds__(256) void lora_fused(const float* __restrict__ x,
                                                  const float* __restrict__ A,
                                                  const float* __restrict__ B,
                                                  float* __restrict__ out) {
  const int tid = threadIdx.x;
  const int lane = tid & 63;
  const int wave = tid >> 6;
  const int jq = wave;           // this wave's j-quad (j = 4*jq .. 4*jq+3)
  const int rbase = blockIdx.x * ROWSB;
  const int m = lane & 3;        // == q&3 for q = kb*64+lane

  __shared__ float4 As[KC * 4];    // 32 KB, swizzled A chunk (r2 layout)
  __shared__ float Ts[ROWSB][RANK];

  const float4* __restrict__ A4 = reinterpret_cast<const float4*>(A);
  const float4* __restrict__ x4 = reinterpret_cast<const float4*>(x);

  // ================= Phase 1: T-tile = x @ A =============
  float vals[32];
#pragma unroll
  for (int i = 0; i < 32; ++i) vals[i] = 0.0f;

  for (int c = 0; c < NCHUNK; ++c) {
    __syncthreads();  // previous chunk's readers done
    // ---- stage chunk c: 2048 float4 slots, 8 per thread (r2 staging) ----
#pragma unroll
    for (int q8 = 0; q8 < 8; ++q8) {
      const int n = q8 * 256 + tid;             // slot index 0..2047
      const int k = n >> 2;                     // local row
      const int s = n & 3;                      // true slot
      const int p = s ^ ((k >> 2) & 3);         // swizzled position
      As[k * 4 + p] = A4[(size_t)c * 2048 + n];
    }
    __syncthreads();

    // ---- compute: 2 k-blocks of 64 k-quads (one quad per lane) ----
#pragma unroll
    for (int kb = 0; kb < 2; ++kb) {
      const int q = kb * 64 + lane;             // local k-quad

      // 8 independent float4 x-loads (8 rows) -- the MLP batch.
      float4 xv[8];
#pragma unroll
      for (int r = 0; r < 8; ++r)
        xv[r] = x4[(size_t)(rbase + r) * (K / 4) + c * (KC / 4) + q];

      // A rows 4q..4q+3, this wave's j-quad (swizzle-inverted).
      float4 a[4];
#pragma unroll
      for (int i = 0; i < 4; ++i)
        a[i] = As[(4 * q + i) * 4 + (jq ^ m)];

#pragma unroll
      for (int r = 0; r < 8; ++r) {
#pragma unroll
        for (int i = 0; i < 4; ++i) {
          const float xs = (i == 0) ? xv[r].x : (i == 1) ? xv[r].y
                          : (i == 2) ? xv[r].z : xv[r].w;
          vals[r * 4 + 0] = fmaf(xs, a[i].x, vals[r * 4 + 0]);
          vals[r * 4 + 1] = fmaf(xs, a[i].y, vals[r * 4 + 1]);
          vals[r * 4 + 2] = fmaf(xs, a[i].z, vals[r * 4 + 2]);
          vals[r * 4 + 3] = fmaf(xs, a[i].w, vals[r * 4 + 3]);
        }
      }
    }
  }

  // 5-fold reduce-scatter over lane bits {32,16,8,4,2} (r7-proven mechanics)
  // then butterfly over bit 1: even lane 2e holds element e (row e>>2, jj e&3).
#define FOLD(AH, LB)                                           \
  {                                                            \
    const bool hi = (lane & (LB)) != 0;                        \
    _Pragma("unroll")                                          \
    for (int i = 0; i < (AH); ++i) {                           \
      const float send = hi ? vals[i] : vals[i + (AH)];        \
      const float keep = hi ? vals[i + (AH)] : vals[i];        \
      vals[i] = keep + __shfl_xor(send, (LB), 64);             \
    }                                                          \
  }
  FOLD(16, 32)
  FOLD(8, 16)
  FOLD(4, 8)
  FOLD(2, 4)
  FOLD(1, 2)
#undef FOLD
  vals[0] += __shfl_xor(vals[0], 1, 64);

  if (!(lane & 1)) {
    const int e = lane >> 1;  // 0..31
    Ts[e >> 2][jq * 4 + (e & 3)] = vals[0];
  }
  __syncthreads();

  // ================= Phase 2: out-tile = T-tile @ B (r9, 8-row tile) ======
  const float4* __restrict__ B4 = reinterpret_cast<const float4*>(B);
  float4* __restrict__ out4 = reinterpret_cast<float4*>(out);

#pragma unroll 1
  for (int cc = 0; cc < 4; ++cc) {
    const int col = wave * 1024 + cc * 256 + lane * 4;

    float4 b[16];
#pragma unroll
    for (int j = 0; j < RANK; ++j) b[j] = B4[((size_t)j * N + col) >> 2];

#pragma unroll 1
    for (int r = 0; r < ROWSB; ++r) {
      // Broadcast T row r (same addr all lanes -> free LDS broadcast).
      const float4* __restrict__ tr4 =
          reinterpret_cast<const float4*>(&Ts[r][0]);
      const float4 t0 = tr4[0];
      const float4 t1 = tr4[1];
      const float4 t2 = tr4[2];
      const float4 t3 = tr4[3];
      const float tsv[16] = {t0.x, t0.y, t0.z, t0.w, t1.x, t1.y, t1.z, t1.w,
                             t2.x, t2.y, t2.z, t2.w, t3.x, t3.y, t3.z, t3.w};

      float4 acc;
      acc.x = acc.y = acc.z = acc.w = 0.0f;
#pragma unroll
      for (int j = 0; j < RANK; ++j) {
        acc.x = fmaf(tsv[j], b[j].x, acc.x);
        acc.y = fmaf(tsv[j], b[j].y, acc.y);
        acc.z = fmaf(tsv[j], b[j].z, acc.z);
        acc.w = fmaf(tsv[j], b[j].w, acc.w);
      }
      out4[((size_t)(rbase + r) * N + col) >> 2] = acc;
    }
  }
}

extern "C" void kernel_launch(void* const* d_in, const int* in_sizes, int n_in,
                              void* d_out, int out_size, void* d_ws, size_t ws_size,
                              hipStream_t stream) {
  const float* x = (const float*)d_in[0];   // [M, K]
  const float* A = (const float*)d_in[1];   // [K, RANK]
  const float* B = (const float*)d_in[2];   // [RANK, N]
  float* out = (float*)d_out;               // [M, N]
  (void)d_ws; (void)ws_size;

  // One fused kernel: 8 rows per block -> 2048 blocks of 256 threads.
  lora_fused<<<M / ROWSB, 256, 0, stream>>>(x, A, B, out);
}